// Round 5
// baseline (222.065 us; speedup 1.0000x reference)
//
#include <hip/hip_runtime.h>
#include <math.h>

#define BB   2
#define NCAM 6
#define CH   256
#define HF   32
#define WF   88
#define NV   100000
#define CIN  128
#define VPB  16          // voxels per block

typedef __attribute__((ext_vector_type(8))) short short8;
typedef __attribute__((ext_vector_type(4))) float f32x4;

static __device__ inline short f2bf(float f) {
    union { float f; unsigned u; } v; v.f = f;
    unsigned r = (v.u + 0x7fffu + ((v.u >> 16) & 1u)) >> 16;  // RNE
    return (short)r;
}
static __device__ inline float bflo(unsigned int pk) {
    union { unsigned int u; float f; } a; a.u = pk << 16; return a.f;
}
static __device__ inline float bfhi(unsigned int pk) {
    union { unsigned int u; float f; } a; a.u = pk & 0xffff0000u; return a.f;
}

// blockIdx 0: params (24 doubles per (b,cam): M[9], v[3], Rpost[9], tpost[3])
// blockIdx 1..64: W[o][c] (128x256 fp32) -> fragment-linear bf16 B-operand
__global__ void prep_params_w(const float* __restrict__ intrins,
                              const float* __restrict__ post_rots,
                              const float* __restrict__ post_trans,
                              const float* __restrict__ bda,
                              const float* __restrict__ l2c,
                              const float* __restrict__ W,
                              double* __restrict__ params,
                              short*  __restrict__ Wbf)
{
    if (blockIdx.x > 0) {
        int chunk = blockIdx.x - 1;      // nt*8+kk, 64 chunks
        int l = threadIdx.x;             // 64 lanes
        int nt = chunk >> 3, kk = chunk & 7;
        int n = nt * 16 + (l & 15);
        int k = kk * 32 + (l >> 4) * 8;
        short v[8];
        #pragma unroll
        for (int j = 0; j < 8; j++) v[j] = f2bf(W[n * CH + k + j]);
        *(short8*)(Wbf + ((size_t)chunk * 64 + l) * 8) = *(short8*)v;
        return;
    }

    int t = threadIdx.x;
    if (t >= BB * NCAM) return;
    int b = t / NCAM;

    const float* Bm = bda + b * 16;
    double a00 = Bm[0], a01 = Bm[1], a02 = Bm[2],  tx = Bm[3];
    double a10 = Bm[4], a11 = Bm[5], a12 = Bm[6],  ty = Bm[7];
    double a20 = Bm[8], a21 = Bm[9], a22 = Bm[10], tz = Bm[11];

    double det = a00*(a11*a22 - a12*a21) - a01*(a10*a22 - a12*a20) + a02*(a10*a21 - a11*a20);
    double id  = 1.0 / det;
    double inv[3][3];
    inv[0][0] =  (a11*a22 - a12*a21) * id;
    inv[0][1] = -(a01*a22 - a02*a21) * id;
    inv[0][2] =  (a01*a12 - a02*a11) * id;
    inv[1][0] = -(a10*a22 - a12*a20) * id;
    inv[1][1] =  (a00*a22 - a02*a20) * id;
    inv[1][2] = -(a00*a12 - a02*a10) * id;
    inv[2][0] =  (a10*a21 - a11*a20) * id;
    inv[2][1] = -(a00*a21 - a01*a20) * id;
    inv[2][2] =  (a00*a11 - a01*a10) * id;

    const float* In = intrins + t * 9;
    const float* Lc = l2c + t * 16;

    double M3[3][3];
    #pragma unroll
    for (int i = 0; i < 3; i++)
        #pragma unroll
        for (int j = 0; j < 3; j++)
            M3[i][j] = (double)In[i*3+0] * (double)Lc[j*4+0]
                     + (double)In[i*3+1] * (double)Lc[j*4+1]
                     + (double)In[i*3+2] * (double)Lc[j*4+2];

    double M[3][3];
    #pragma unroll
    for (int i = 0; i < 3; i++)
        #pragma unroll
        for (int j = 0; j < 3; j++)
            M[i][j] = M3[i][0]*inv[0][j] + M3[i][1]*inv[1][j] + M3[i][2]*inv[2][j];

    double* P = params + t * 24;
    #pragma unroll
    for (int i = 0; i < 3; i++)
        #pragma unroll
        for (int j = 0; j < 3; j++)
            P[i*3+j] = M[i][j];
    #pragma unroll
    for (int i = 0; i < 3; i++)
        P[9+i] = -(M[i][0]*tx + M[i][1]*ty + M[i][2]*tz);
    #pragma unroll
    for (int i = 0; i < 9; i++) P[12+i] = (double)post_rots[t*9 + i];
    #pragma unroll
    for (int i = 0; i < 3; i++) P[21+i] = (double)post_trans[t*3 + i];
}

// img[b,c,ch,y,x] (fp32) -> imgT[(bc*HF+y)*WF + x][ch] (bf16, channel-contiguous)
__global__ __launch_bounds__(256) void transpose_img(const float* __restrict__ img,
                                                     unsigned short* __restrict__ imgT)
{
    __shared__ float tile[32][89];
    int bid = blockIdx.x;
    int cg  = bid & 7;           // 32-channel group
    int y   = (bid >> 3) & 31;
    int bc  = bid >> 8;          // 0..11
    int t   = threadIdx.x;

    const float* src = img + ((size_t)(bc * CH + cg * 32)) * (HF * WF) + y * WF;
    #pragma unroll
    for (int i = 0; i < 11; i++) {           // 32*88 = 2816 = 11*256
        int lin = i * 256 + t;
        int ch  = lin / 88;
        int x   = lin - ch * 88;
        tile[ch][x] = src[(size_t)ch * (HF * WF) + x];
    }
    __syncthreads();

    unsigned short* dst = imgT + ((size_t)(bc * HF + y) * WF) * CH + cg * 32;
    #pragma unroll
    for (int j = 0; j < 6; j++) {
        int lin2 = j * 256 + t;
        if (j == 5 && t >= 128) break;
        int x  = lin2 >> 4;
        int cp = lin2 & 15;
        unsigned short lo = (unsigned short)f2bf(tile[2 * cp][x]);
        unsigned short hi = (unsigned short)f2bf(tile[2 * cp + 1][x]);
        unsigned int pk = (unsigned int)lo | ((unsigned int)hi << 16);
        *(unsigned int*)(dst + (size_t)x * CH + 2 * cp) = pk;
    }
}

struct POF { int o; float m; };

template <bool TRANS>
__global__ __launch_bounds__(256) void fused_gather_mm(
    const float*  __restrict__ vf,
    const int*    __restrict__ coords,
    const void*   __restrict__ imgv,    // bf16 imgT if TRANS, fp32 img otherwise
    const double* __restrict__ params,
    const short*  __restrict__ Wbf,     // fragment-linear bf16 W^T
    float*        __restrict__ out)
{
    const int t  = threadIdx.x;
    const int n0 = blockIdx.x * VPB;

    // ---- passthrough copies ----
    {
        const float4* vf4 = (const float4*)vf;
        float4*       o4  = (float4*)out;
        int base = n0 * (CIN / 4);
        o4[base + t]       = vf4[base + t];
        o4[base + 256 + t] = vf4[base + 256 + t];
    }
    if (t < VPB * 4) {
        int gi = n0 * 4 + t;
        float cv = (float)coords[gi];
        const size_t cb = (size_t)2 * NV * CIN;
        out[cb + gi]                  = cv;
        out[cb + (size_t)NV * 4 + gi] = cv;
    }

    __shared__ POF pof[VPB][NCAM];                       // 768 B
    __shared__ __align__(16) short aFrag[8 * 64 * 8];    // 8 KB, fragment-linear A

    // ---- fp64 projection: one thread per (voxel, cam) ----
    if (t < VPB * NCAM) {
        int vi = t / NCAM, c = t - vi * NCAM;
        int n  = n0 + vi;
        int b  = coords[n * 4 + 0];
        int zi = coords[n * 4 + 1];
        int yi = coords[n * 4 + 2];
        int xi = coords[n * 4 + 3];
        double px = (double)xi * (double)0.075f + (-54.0);
        double py = (double)yi * (double)0.075f + (-54.0);
        double pz = (double)zi * (double)0.2f   + (-5.0);
        const double* P = params + (b * NCAM + c) * 24;
        double X = P[0]*px + P[1]*py + P[2]*pz + P[9];
        double Y = P[3]*px + P[4]*py + P[5]*pz + P[10];
        double Z = P[6]*px + P[7]*py + P[8]*pz + P[11];
        double u = X / Z;
        double v = Y / Z;
        double q0 = P[12]*u + P[13]*v + P[14]*Z + P[21];
        double q1 = P[15]*u + P[16]*v + P[17]*Z + P[22];
        double q2 = P[18]*u + P[19]*v + P[20]*Z + P[23];
        double cx = rint(q0 * 0.125);
        double cy = rint(q1 * 0.125);
        bool m = (cx >= 0.0) && (cx < (double)WF) && (cy >= 0.0) && (cy < (double)HF)
              && (q2 < 60.0) && (q2 >= 1.0);
        int o = 0;
        if (m) {
            int ix = (int)cx, iy = (int)cy;
            if (TRANS) o = ((b * NCAM + c) * HF + iy) * WF + ix;            // pixel idx
            else       o = (b * NCAM + c) * (CH * HF * WF) + iy * WF + ix;  // ch0 elem
        }
        POF p2; p2.o = o; p2.m = m ? 1.0f : 0.0f;
        pof[vi][c] = p2;
    }
    __syncthreads();

    // ---- gather directly into A-fragment registers ----
    // thread owns voxel vi = t&15, fragment slots c2a = kk*64 + l and c2b = (kk+4)*64 + l
    // (l = t&63, kk = t>>6) -> channels [k0, k0+8) and [k0+128, k0+136)
    {
        const int l  = t & 63;
        const int kk = t >> 6;
        const int vi = l & 15;
        const int k0 = kk * 32 + ((l >> 4) & 3) * 8;

        float g[16];
        #pragma unroll
        for (int j = 0; j < 16; j++) g[j] = 0.0f;

        if (TRANS) {
            const unsigned short* imgT = (const unsigned short*)imgv;
            #pragma unroll
            for (int c = 0; c < NCAM; c++) {
                POF p2 = pof[vi][c];
                float w = p2.m;
                const unsigned short* px = imgT + (size_t)p2.o * CH;
                uint4 A = *(const uint4*)(px + k0);
                uint4 B2 = *(const uint4*)(px + k0 + 128);
                g[0]  = fmaf(w, bflo(A.x),  g[0]);  g[1]  = fmaf(w, bfhi(A.x),  g[1]);
                g[2]  = fmaf(w, bflo(A.y),  g[2]);  g[3]  = fmaf(w, bfhi(A.y),  g[3]);
                g[4]  = fmaf(w, bflo(A.z),  g[4]);  g[5]  = fmaf(w, bfhi(A.z),  g[5]);
                g[6]  = fmaf(w, bflo(A.w),  g[6]);  g[7]  = fmaf(w, bfhi(A.w),  g[7]);
                g[8]  = fmaf(w, bflo(B2.x), g[8]);  g[9]  = fmaf(w, bfhi(B2.x), g[9]);
                g[10] = fmaf(w, bflo(B2.y), g[10]); g[11] = fmaf(w, bfhi(B2.y), g[11]);
                g[12] = fmaf(w, bflo(B2.z), g[12]); g[13] = fmaf(w, bfhi(B2.z), g[13]);
                g[14] = fmaf(w, bflo(B2.w), g[14]); g[15] = fmaf(w, bfhi(B2.w), g[15]);
            }
        } else {
            const float* img = (const float*)imgv;
            #pragma unroll
            for (int c = 0; c < NCAM; c++) {
                POF p2 = pof[vi][c];
                float w = p2.m;
                #pragma unroll
                for (int j = 0; j < 8; j++) {
                    g[j]     = fmaf(w, img[(size_t)(k0 + j)       * (HF * WF) + p2.o], g[j]);
                    g[8 + j] = fmaf(w, img[(size_t)(k0 + 128 + j) * (HF * WF) + p2.o], g[8 + j]);
                }
            }
        }

        short tmp[16];
        #pragma unroll
        for (int j = 0; j < 16; j++) tmp[j] = f2bf(g[j]);
        *(short8*)(aFrag + (kk * 64 + l) * 8)       = *(short8*)&tmp[0];
        *(short8*)(aFrag + ((kk + 4) * 64 + l) * 8) = *(short8*)&tmp[8];
    }
    __syncthreads();

    // ---- MFMA: each wave computes C[16 voxels][32 outputs] ----
    {
        const int w    = t >> 6;
        const int lane = t & 63;
        f32x4 acc0 = {0.f, 0.f, 0.f, 0.f};
        f32x4 acc1 = {0.f, 0.f, 0.f, 0.f};
        const short8* Bf = (const short8*)Wbf;
        #pragma unroll
        for (int kk = 0; kk < 8; kk++) {
            short8 a  = *(const short8*)(aFrag + (kk * 64 + lane) * 8);
            short8 b0 = Bf[((2 * w)     * 8 + kk) * 64 + lane];
            short8 b1 = Bf[((2 * w + 1) * 8 + kk) * 64 + lane];
            acc0 = __builtin_amdgcn_mfma_f32_16x16x32_bf16(a, b0, acc0, 0, 0, 0);
            acc1 = __builtin_amdgcn_mfma_f32_16x16x32_bf16(a, b1, acc1, 0, 0, 0);
        }
        float* oiv = out + (size_t)NV * CIN;
        int col = lane & 15, rq = lane >> 4;
        #pragma unroll
        for (int r = 0; r < 4; r++) {
            int n = n0 + rq * 4 + r;
            oiv[(size_t)n * CIN + (2 * w)     * 16 + col] = acc0[r];
            oiv[(size_t)n * CIN + (2 * w + 1) * 16 + col] = acc1[r];
        }
    }
}

extern "C" void kernel_launch(void* const* d_in, const int* in_sizes, int n_in,
                              void* d_out, int out_size, void* d_ws, size_t ws_size,
                              hipStream_t stream)
{
    const float* vf      = (const float*)d_in[0];
    const int*   coords  = (const int*)d_in[1];
    const float* img     = (const float*)d_in[2];
    const float* intrins = (const float*)d_in[3];
    const float* prots   = (const float*)d_in[4];
    const float* ptrans  = (const float*)d_in[5];
    const float* bda     = (const float*)d_in[6];
    const float* l2c     = (const float*)d_in[7];
    const float* W       = (const float*)d_in[8];
    float* out = (float*)d_out;

    double* params = (double*)d_ws;
    const size_t wbf_off  = 4096;
    const size_t wbf_sz   = (size_t)8 * 8 * 64 * 8 * sizeof(short);  // 64 KB
    const size_t imgT_off = wbf_off + wbf_sz;
    const size_t needed   = imgT_off + (size_t)BB * NCAM * HF * WF * CH * sizeof(unsigned short);

    short* Wbf = (short*)((char*)d_ws + wbf_off);

    prep_params_w<<<65, 64, 0, stream>>>(intrins, prots, ptrans, bda, l2c, W, params, Wbf);

    if (ws_size >= needed) {
        unsigned short* imgT = (unsigned short*)((char*)d_ws + imgT_off);
        transpose_img<<<BB * NCAM * HF * 8, 256, 0, stream>>>(img, imgT);
        fused_gather_mm<true><<<NV / VPB, 256, 0, stream>>>(vf, coords, imgT, params, Wbf, out);
    } else {
        fused_gather_mm<false><<<NV / VPB, 256, 0, stream>>>(vf, coords, img, params, Wbf, out);
    }
}

// Round 6
// 218.724 us; speedup vs baseline: 1.0153x; 1.0153x over previous
//
#include <hip/hip_runtime.h>
#include <math.h>

#define BB   2
#define NCAM 6
#define CH   256
#define HF   32
#define WF   88
#define NV   100000
#define CIN  128
#define VPB  32          // voxels per block (2 MFMA A-tiles)

typedef __attribute__((ext_vector_type(8))) short short8;
typedef __attribute__((ext_vector_type(4))) float f32x4;

static __device__ inline short f2bf(float f) {
    union { float f; unsigned u; } v; v.f = f;
    unsigned r = (v.u + 0x7fffu + ((v.u >> 16) & 1u)) >> 16;  // RNE
    return (short)r;
}
static __device__ inline float bflo(unsigned int pk) {
    union { unsigned int u; float f; } a; a.u = pk << 16; return a.f;
}
static __device__ inline float bfhi(unsigned int pk) {
    union { unsigned int u; float f; } a; a.u = pk & 0xffff0000u; return a.f;
}

// blockIdx 0: params (24 doubles per (b,cam): M[9], v[3], Rpost[9], tpost[3])
// blockIdx 1..64: W[o][c] (128x256 fp32) -> fragment-linear bf16 B-operand
__global__ void prep_params_w(const float* __restrict__ intrins,
                              const float* __restrict__ post_rots,
                              const float* __restrict__ post_trans,
                              const float* __restrict__ bda,
                              const float* __restrict__ l2c,
                              const float* __restrict__ W,
                              double* __restrict__ params,
                              short*  __restrict__ Wbf)
{
    if (blockIdx.x > 0) {
        int chunk = blockIdx.x - 1;      // nt*8+kk, 64 chunks
        int l = threadIdx.x;             // 64 lanes
        int nt = chunk >> 3, kk = chunk & 7;
        int n = nt * 16 + (l & 15);
        int k = kk * 32 + (l >> 4) * 8;
        short v[8];
        #pragma unroll
        for (int j = 0; j < 8; j++) v[j] = f2bf(W[n * CH + k + j]);
        *(short8*)(Wbf + ((size_t)chunk * 64 + l) * 8) = *(short8*)v;
        return;
    }

    int t = threadIdx.x;
    if (t >= BB * NCAM) return;
    int b = t / NCAM;

    const float* Bm = bda + b * 16;
    double a00 = Bm[0], a01 = Bm[1], a02 = Bm[2],  tx = Bm[3];
    double a10 = Bm[4], a11 = Bm[5], a12 = Bm[6],  ty = Bm[7];
    double a20 = Bm[8], a21 = Bm[9], a22 = Bm[10], tz = Bm[11];

    double det = a00*(a11*a22 - a12*a21) - a01*(a10*a22 - a12*a20) + a02*(a10*a21 - a11*a20);
    double id  = 1.0 / det;
    double inv[3][3];
    inv[0][0] =  (a11*a22 - a12*a21) * id;
    inv[0][1] = -(a01*a22 - a02*a21) * id;
    inv[0][2] =  (a01*a12 - a02*a11) * id;
    inv[1][0] = -(a10*a22 - a12*a20) * id;
    inv[1][1] =  (a00*a22 - a02*a20) * id;
    inv[1][2] = -(a00*a12 - a02*a10) * id;
    inv[2][0] =  (a10*a21 - a11*a20) * id;
    inv[2][1] = -(a00*a21 - a01*a20) * id;
    inv[2][2] =  (a00*a11 - a01*a10) * id;

    const float* In = intrins + t * 9;
    const float* Lc = l2c + t * 16;

    double M3[3][3];
    #pragma unroll
    for (int i = 0; i < 3; i++)
        #pragma unroll
        for (int j = 0; j < 3; j++)
            M3[i][j] = (double)In[i*3+0] * (double)Lc[j*4+0]
                     + (double)In[i*3+1] * (double)Lc[j*4+1]
                     + (double)In[i*3+2] * (double)Lc[j*4+2];

    double M[3][3];
    #pragma unroll
    for (int i = 0; i < 3; i++)
        #pragma unroll
        for (int j = 0; j < 3; j++)
            M[i][j] = M3[i][0]*inv[0][j] + M3[i][1]*inv[1][j] + M3[i][2]*inv[2][j];

    double* P = params + t * 24;
    #pragma unroll
    for (int i = 0; i < 3; i++)
        #pragma unroll
        for (int j = 0; j < 3; j++)
            P[i*3+j] = M[i][j];
    #pragma unroll
    for (int i = 0; i < 3; i++)
        P[9+i] = -(M[i][0]*tx + M[i][1]*ty + M[i][2]*tz);
    #pragma unroll
    for (int i = 0; i < 9; i++) P[12+i] = (double)post_rots[t*9 + i];
    #pragma unroll
    for (int i = 0; i < 3; i++) P[21+i] = (double)post_trans[t*3 + i];
}

// img[b,c,ch,y,x] (fp32) -> imgT[(bc*HF+y)*WF + x][ch] (bf16, channel-contiguous)
__global__ __launch_bounds__(256) void transpose_img(const float* __restrict__ img,
                                                     unsigned short* __restrict__ imgT)
{
    __shared__ float tile[32][89];
    int bid = blockIdx.x;
    int cg  = bid & 7;           // 32-channel group
    int y   = (bid >> 3) & 31;
    int bc  = bid >> 8;          // 0..11
    int t   = threadIdx.x;

    const float* src = img + ((size_t)(bc * CH + cg * 32)) * (HF * WF) + y * WF;
    #pragma unroll
    for (int i = 0; i < 11; i++) {           // 32*88 = 2816 = 11*256
        int lin = i * 256 + t;
        int ch  = lin / 88;
        int x   = lin - ch * 88;
        tile[ch][x] = src[(size_t)ch * (HF * WF) + x];
    }
    __syncthreads();

    unsigned short* dst = imgT + ((size_t)(bc * HF + y) * WF) * CH + cg * 32;
    #pragma unroll
    for (int j = 0; j < 6; j++) {
        int lin2 = j * 256 + t;
        if (j == 5 && t >= 128) break;
        int x  = lin2 >> 4;
        int cp = lin2 & 15;
        unsigned short lo = (unsigned short)f2bf(tile[2 * cp][x]);
        unsigned short hi = (unsigned short)f2bf(tile[2 * cp + 1][x]);
        unsigned int pk = (unsigned int)lo | ((unsigned int)hi << 16);
        *(unsigned int*)(dst + (size_t)x * CH + 2 * cp) = pk;
    }
}

struct POF { int o; float m; };

template <bool TRANS>
__global__ __launch_bounds__(256) void fused_gather_mm(
    const float*  __restrict__ vf,
    const int*    __restrict__ coords,
    const void*   __restrict__ imgv,    // bf16 imgT if TRANS, fp32 img otherwise
    const double* __restrict__ params,
    const short*  __restrict__ Wbf,     // fragment-linear bf16 W^T
    float*        __restrict__ out)
{
    const int t  = threadIdx.x;
    const int n0 = blockIdx.x * VPB;

    // ---- passthrough copies: 32 vox x 128 ch = 1024 float4 ----
    {
        const float4* vf4 = (const float4*)vf;
        float4*       o4  = (float4*)out;
        int base = n0 * (CIN / 4);
        #pragma unroll
        for (int i = 0; i < 4; i++)
            o4[base + i * 256 + t] = vf4[base + i * 256 + t];
    }
    if (t < VPB * 4) {
        int gi = n0 * 4 + t;
        float cv = (float)coords[gi];
        const size_t cb = (size_t)2 * NV * CIN;
        out[cb + gi]                  = cv;
        out[cb + (size_t)NV * 4 + gi] = cv;
    }

    __shared__ POF pof[VPB][NCAM];                        // 1.5 KB
    __shared__ __align__(16) short aFrag[16 * 64 * 8];    // 16 KB, fragment-linear A (2 tiles)

    // ---- fp64 projection: one thread per (voxel, cam), 192 pairs ----
    if (t < VPB * NCAM) {
        int vi = t / NCAM, c = t - vi * NCAM;
        int n  = n0 + vi;
        int b  = coords[n * 4 + 0];
        int zi = coords[n * 4 + 1];
        int yi = coords[n * 4 + 2];
        int xi = coords[n * 4 + 3];
        double px = (double)xi * (double)0.075f + (-54.0);
        double py = (double)yi * (double)0.075f + (-54.0);
        double pz = (double)zi * (double)0.2f   + (-5.0);
        const double* P = params + (b * NCAM + c) * 24;
        double X = P[0]*px + P[1]*py + P[2]*pz + P[9];
        double Y = P[3]*px + P[4]*py + P[5]*pz + P[10];
        double Z = P[6]*px + P[7]*py + P[8]*pz + P[11];
        double u = X / Z;
        double v = Y / Z;
        double q0 = P[12]*u + P[13]*v + P[14]*Z + P[21];
        double q1 = P[15]*u + P[16]*v + P[17]*Z + P[22];
        double q2 = P[18]*u + P[19]*v + P[20]*Z + P[23];
        double cx = rint(q0 * 0.125);
        double cy = rint(q1 * 0.125);
        bool m = (cx >= 0.0) && (cx < (double)WF) && (cy >= 0.0) && (cy < (double)HF)
              && (q2 < 60.0) && (q2 >= 1.0);
        int o = 0;
        if (m) {
            int ix = (int)cx, iy = (int)cy;
            if (TRANS) o = ((b * NCAM + c) * HF + iy) * WF + ix;            // pixel idx
            else       o = (b * NCAM + c) * (CH * HF * WF) + iy * WF + ix;  // ch0 elem
        }
        POF p2; p2.o = o; p2.m = m ? 1.0f : 0.0f;
        pof[vi][c] = p2;
    }
    __syncthreads();

    // ---- gather directly into A-fragment registers ----
    // wave w: A-tile vt = w>>1, K-chunks kk = (w&1)*4 .. +4
    // lane l: voxel vi = vt*16 + (l&15), channel quad q = l>>4
    // per (kk): 8 channels [kk*32 + q*8, +8)  -> 24 independent dwordx4 loads
    {
        const int l   = t & 63;
        const int w   = t >> 6;
        const int vt  = w >> 1;
        const int kb  = (w & 1) * 4;
        const int vi  = vt * 16 + (l & 15);
        const int q   = l >> 4;

        float g[4][8];
        #pragma unroll
        for (int i = 0; i < 4; i++)
            #pragma unroll
            for (int j = 0; j < 8; j++) g[i][j] = 0.0f;

        if (TRANS) {
            const unsigned short* imgT = (const unsigned short*)imgv;
            #pragma unroll
            for (int c = 0; c < NCAM; c++) {
                POF p2 = pof[vi][c];
                float wm = p2.m;
                const unsigned short* px = imgT + (size_t)p2.o * CH + q * 8;
                #pragma unroll
                for (int k2 = 0; k2 < 4; k2++) {
                    uint4 A = *(const uint4*)(px + (kb + k2) * 32);
                    g[k2][0] = fmaf(wm, bflo(A.x), g[k2][0]);
                    g[k2][1] = fmaf(wm, bfhi(A.x), g[k2][1]);
                    g[k2][2] = fmaf(wm, bflo(A.y), g[k2][2]);
                    g[k2][3] = fmaf(wm, bfhi(A.y), g[k2][3]);
                    g[k2][4] = fmaf(wm, bflo(A.z), g[k2][4]);
                    g[k2][5] = fmaf(wm, bfhi(A.z), g[k2][5]);
                    g[k2][6] = fmaf(wm, bflo(A.w), g[k2][6]);
                    g[k2][7] = fmaf(wm, bfhi(A.w), g[k2][7]);
                }
            }
        } else {
            const float* img = (const float*)imgv;
            #pragma unroll
            for (int c = 0; c < NCAM; c++) {
                POF p2 = pof[vi][c];
                float wm = p2.m;
                #pragma unroll
                for (int k2 = 0; k2 < 4; k2++) {
                    int k0 = (kb + k2) * 32 + q * 8;
                    #pragma unroll
                    for (int j = 0; j < 8; j++)
                        g[k2][j] = fmaf(wm, img[(size_t)(k0 + j) * (HF * WF) + p2.o], g[k2][j]);
                }
            }
        }

        #pragma unroll
        for (int k2 = 0; k2 < 4; k2++) {
            short tmp[8];
            #pragma unroll
            for (int j = 0; j < 8; j++) tmp[j] = f2bf(g[k2][j]);
            int chunk = vt * 8 + kb + k2;               // [0,16)
            *(short8*)(aFrag + (chunk * 64 + l) * 8) = *(short8*)tmp;
        }
    }
    __syncthreads();

    // ---- MFMA: wave w -> B-tiles {2w, 2w+1} x A-tiles {0,1} ----
    {
        const int w    = t >> 6;
        const int lane = t & 63;
        f32x4 acc[2][2];
        #pragma unroll
        for (int a2 = 0; a2 < 2; a2++)
            #pragma unroll
            for (int b2 = 0; b2 < 2; b2++)
                acc[a2][b2] = (f32x4){0.f, 0.f, 0.f, 0.f};
        const short8* Bf = (const short8*)Wbf;
        #pragma unroll
        for (int kk = 0; kk < 8; kk++) {
            short8 b0 = Bf[((2 * w)     * 8 + kk) * 64 + lane];
            short8 b1 = Bf[((2 * w + 1) * 8 + kk) * 64 + lane];
            short8 a0 = *(const short8*)(aFrag + ((0 * 8 + kk) * 64 + lane) * 8);
            short8 a1 = *(const short8*)(aFrag + ((1 * 8 + kk) * 64 + lane) * 8);
            acc[0][0] = __builtin_amdgcn_mfma_f32_16x16x32_bf16(a0, b0, acc[0][0], 0, 0, 0);
            acc[0][1] = __builtin_amdgcn_mfma_f32_16x16x32_bf16(a0, b1, acc[0][1], 0, 0, 0);
            acc[1][0] = __builtin_amdgcn_mfma_f32_16x16x32_bf16(a1, b0, acc[1][0], 0, 0, 0);
            acc[1][1] = __builtin_amdgcn_mfma_f32_16x16x32_bf16(a1, b1, acc[1][1], 0, 0, 0);
        }
        // C/D: col = lane&15 (output), row = (lane>>4)*4 + r (voxel)
        float* oiv = out + (size_t)NV * CIN;
        int col = lane & 15, rq = lane >> 4;
        #pragma unroll
        for (int a2 = 0; a2 < 2; a2++) {
            #pragma unroll
            for (int r = 0; r < 4; r++) {
                int n = n0 + a2 * 16 + rq * 4 + r;
                oiv[(size_t)n * CIN + (2 * w)     * 16 + col] = acc[a2][0][r];
                oiv[(size_t)n * CIN + (2 * w + 1) * 16 + col] = acc[a2][1][r];
            }
        }
    }
}

extern "C" void kernel_launch(void* const* d_in, const int* in_sizes, int n_in,
                              void* d_out, int out_size, void* d_ws, size_t ws_size,
                              hipStream_t stream)
{
    const float* vf      = (const float*)d_in[0];
    const int*   coords  = (const int*)d_in[1];
    const float* img     = (const float*)d_in[2];
    const float* intrins = (const float*)d_in[3];
    const float* prots   = (const float*)d_in[4];
    const float* ptrans  = (const float*)d_in[5];
    const float* bda     = (const float*)d_in[6];
    const float* l2c     = (const float*)d_in[7];
    const float* W       = (const float*)d_in[8];
    float* out = (float*)d_out;

    double* params = (double*)d_ws;
    const size_t wbf_off  = 4096;
    const size_t wbf_sz   = (size_t)8 * 8 * 64 * 8 * sizeof(short);  // 64 KB
    const size_t imgT_off = wbf_off + wbf_sz;
    const size_t needed   = imgT_off + (size_t)BB * NCAM * HF * WF * CH * sizeof(unsigned short);

    short* Wbf = (short*)((char*)d_ws + wbf_off);

    prep_params_w<<<65, 64, 0, stream>>>(intrins, prots, ptrans, bda, l2c, W, params, Wbf);

    if (ws_size >= needed) {
        unsigned short* imgT = (unsigned short*)((char*)d_ws + imgT_off);
        transpose_img<<<BB * NCAM * HF * 8, 256, 0, stream>>>(img, imgT);
        fused_gather_mm<true><<<NV / VPB, 256, 0, stream>>>(vf, coords, imgT, params, Wbf, out);
    } else {
        fused_gather_mm<false><<<NV / VPB, 256, 0, stream>>>(vf, coords, img, params, Wbf, out);
    }
}